// Round 9
// baseline (49.730 us; speedup 1.0000x reference)
//
#include <hip/hip_runtime.h>

typedef __attribute__((ext_vector_type(8))) short short8;
typedef __attribute__((ext_vector_type(4))) float f32x4;
typedef __attribute__((ext_vector_type(4))) unsigned short u16x4;

#define DI __device__ __forceinline__

namespace {
constexpr int TOT_ = 512;     // output row width (floats)
constexpr int XROW = 2048;    // x row width (floats) = F*D
constexpr int NB_  = 1024;    // persistent: 64 features x 16 blocks, 4 items each
}

DI unsigned short f2bf(float v) {
    __bf16 h = (__bf16)v;     // RNE convert
    return __builtin_bit_cast(unsigned short, h);
}

__global__ __launch_bounds__(256)
void recon_kernel(const float* __restrict__ x, const float* __restrict__ W1,
                  const float* __restrict__ b1, const float* __restrict__ W2,
                  const float* __restrict__ b2, float* __restrict__ out)
{
    __shared__ __align__(16) unsigned short w1t[64 * 32];    // [n<64][k<32]
    __shared__ __align__(16) unsigned short w2t[32 * 64];    // [n<32][k<64]
    __shared__ __align__(16) unsigned short hb[4][16 * 64];  // per-wave h^T tile

    const int bid = blockIdx.x;                 // 0..1023
    const int f   = bid & 63;                   // block keeps f for its whole life
    const int bq  = bid >> 6;                   // 0..15; items: btile = bq + j*16

    const int tid  = threadIdx.x;
    const int lane = tid & 63;
    const int wv   = tid >> 6;
    const int l15  = lane & 15;
    const int kg   = lane >> 4;
    const int swz  = (l15 & 7) << 3;            // XOR swizzle (16-B granule)
    const bool catf = (f < 32);                 // categorical (card>1)?

    const float* xcol = x + f * 32 + kg * 8;    // + row*XROW per access

    // ---- prologue: issue item-0 x loads first (HBM latency hides under
    //      the weight staging + barrier below) ----
    f32x4 xs[4][2];
    {
        const int rb = bq * 256 + wv * 64 + l15;
#pragma unroll
        for (int t = 0; t < 4; ++t) {
            const float* p = xcol + (size_t)(rb + t * 16) * XROW;
            xs[t][0] = *(const f32x4*)p;
            xs[t][1] = *(const f32x4*)(p + 4);
        }
    }

    // ---- stage W1^T and W2^T into LDS as bf16 (ONCE per 1024 rows) ----
    {
        const int e0 = tid * 8;                 // 256 thr x 8 = 2048 elements
        const float* W1f = W1 + f * 2048;
        const float* W2f = W2 + f * 2048;
        f32x4 v0 = *(const f32x4*)(W1f + e0);
        f32x4 v1 = *(const f32x4*)(W1f + e0 + 4);
        f32x4 u0 = *(const f32x4*)(W2f + e0);
        f32x4 u1 = *(const f32x4*)(W2f + e0 + 4);
#pragma unroll
        for (int j = 0; j < 8; ++j) {
            int e = e0 + j;
            float v = (j < 4) ? v0[j] : v1[j - 4];
            w1t[(e & 63) * 32 + (e >> 6)] = f2bf(v);   // W1: e = k*64 + n
            float u = (j < 4) ? u0[j] : u1[j - 4];
            w2t[(e & 31) * 64 + (e >> 5)] = f2bf(u);   // W2: e = k*32 + n
        }
    }
    __syncthreads();                            // the ONLY barrier in the kernel

    // ---- fragments (swapped-operand layout) ----
    short8 w1b[4];                               // W1[k][c]: c=l15, k=kg*8+j
#pragma unroll
    for (int nt = 0; nt < 4; ++nt)
        w1b[nt] = *(const short8*)&w1t[(nt * 16 + l15) * 32 + kg * 8];

    short8 w2b[2][2] = {};                       // W2[k][c]: c=l15, k=ks*32+kg*8+j
    if (catf) {
#pragma unroll
        for (int nt = 0; nt < 2; ++nt)
#pragma unroll
            for (int ks = 0; ks < 2; ++ks)
                w2b[nt][ks] = *(const short8*)&w2t[(nt * 16 + l15) * 64 + ks * 32 + kg * 8];
    } else {
        // card==1: only output column 0 used; W2^T column n=0 is contiguous in k
#pragma unroll
        for (int ks = 0; ks < 2; ++ks)
            w2b[0][ks] = *(const short8*)&w2t[ks * 32 + kg * 8];
    }

    f32x4 b1q[4], b2q[2];                        // fed as MFMA C-operand
#pragma unroll
    for (int nt = 0; nt < 4; ++nt) b1q[nt] = *(const f32x4*)(b1 + f * 64 + nt * 16 + kg * 4);
#pragma unroll
    for (int nt = 0; nt < 2; ++nt) b2q[nt] = *(const f32x4*)(b2 + f * 32 + nt * 16 + kg * 4);

    // output gather params (CARDS = [4,8,16,32]*8 ++ [1]*32)
    int card, off;
    if (catf) { card = 4 << (f & 3); off = (f >> 2) * 60 + card - 4; }
    else      { card = 1;            off = 480 + (f - 32); }

    unsigned short* hw = hb[wv];

    // ---- 4 items x 4 tiles, cross-item rolling pipeline (4 loads in flight) ----
#pragma unroll
    for (int j = 0; j < 4; ++j) {
        const int r0 = (bq + j * 16) * 256 + wv * 64;
#pragma unroll
        for (int t = 0; t < 4; ++t) {
            short8 af;                           // x[r=l15][k=kg*8+j]
#pragma unroll
            for (int q = 0; q < 4; ++q) {
                af[q]     = (short)f2bf(xs[t][0][q]);
                af[4 + q] = (short)f2bf(xs[t][1][q]);
            }
            if (j < 3) {                         // refill slot t from item j+1
                const float* p = xcol + (size_t)((bq + (j + 1) * 16) * 256
                                                 + wv * 64 + t * 16 + l15) * XROW;
                xs[t][0] = *(const f32x4*)p;
                xs[t][1] = *(const f32x4*)(p + 4);
            }

            // GEMM1 swapped, bias in acc: lane holds h[c=nt*16+kg*4+q][r=l15]
            f32x4 c1[4];
#pragma unroll
            for (int nt = 0; nt < 4; ++nt)
                c1[nt] = __builtin_amdgcn_mfma_f32_16x16x32_bf16(w1b[nt], af, b1q[nt], 0, 0, 0);

            // ReLU -> packed bf16x4 -> wave-private swizzled LDS (no barrier)
#pragma unroll
            for (int nt = 0; nt < 4; ++nt) {
                u16x4 hv;
#pragma unroll
                for (int q = 0; q < 4; ++q) {
                    float v = c1[nt][q];
                    hv[q] = f2bf(v > 0.f ? v : 0.f);
                }
                *(u16x4*)&hw[(l15 * 64 + nt * 16 + kg * 4) ^ swz] = hv;
            }

            // GEMM2 A-fragments (h[r=l15][k=ks*32+kg*8+q]) from swizzled LDS
            short8 ha[2];
#pragma unroll
            for (int ks = 0; ks < 2; ++ks)
                ha[ks] = *(const short8*)&hw[(l15 * 64 + ks * 32 + kg * 8) ^ swz];

            // GEMM2 swapped, bias in acc: lane holds out[c=nt*16+kg*4+q][r=l15]
            f32x4 c2[2];
            c2[0] = __builtin_amdgcn_mfma_f32_16x16x32_bf16(w2b[0][0], ha[0], b2q[0], 0, 0, 0);
            c2[0] = __builtin_amdgcn_mfma_f32_16x16x32_bf16(w2b[0][1], ha[1], c2[0], 0, 0, 0);
            if (card == 32) {
                c2[1] = __builtin_amdgcn_mfma_f32_16x16x32_bf16(w2b[1][0], ha[0], b2q[1], 0, 0, 0);
                c2[1] = __builtin_amdgcn_mfma_f32_16x16x32_bf16(w2b[1][1], ha[1], c2[1], 0, 0, 0);
            }

            // store: each active lane writes one aligned dwordx4 (bias already in)
            const int row = r0 + t * 16 + l15;
            if (card > 1) {
                const int ntiles = (card == 32) ? 2 : 1;
                for (int nt = 0; nt < ntiles; ++nt) {
                    if (kg * 4 < card - nt * 16) {
                        f32x4 v;
#pragma unroll
                        for (int q = 0; q < 4; ++q) v[q] = c2[nt][q];
                        *(f32x4*)(out + (size_t)row * TOT_ + off + nt * 16 + kg * 4) = v;
                    }
                }
            } else {
                if (kg == 0)
                    out[(size_t)row * TOT_ + off] = c2[0][0];
            }
        }
    }
}

extern "C" void kernel_launch(void* const* d_in, const int* in_sizes, int n_in,
                              void* d_out, int out_size, void* d_ws, size_t ws_size,
                              hipStream_t stream) {
    const float* x  = (const float*)d_in[0];
    const float* W1 = (const float*)d_in[1];
    const float* b1 = (const float*)d_in[2];
    const float* W2 = (const float*)d_in[3];
    const float* b2 = (const float*)d_in[4];
    float* out = (float*)d_out;
    recon_kernel<<<NB_, 256, 0, stream>>>(x, W1, b1, W2, b2, out);
}

// Round 11
// 40.038 us; speedup vs baseline: 1.2421x; 1.2421x over previous
//
#include <hip/hip_runtime.h>

typedef __attribute__((ext_vector_type(8))) short short8;
typedef __attribute__((ext_vector_type(4))) float f32x4;
typedef __attribute__((ext_vector_type(4))) unsigned short u16x4;

#define DI __device__ __forceinline__

namespace {
constexpr int TOT_ = 512;                 // output row width (floats)
constexpr int XROW = 2048;                // x row width (floats) = F*D
constexpr int BT_  = 256;                 // batch rows per block
constexpr int NB_  = (16384 / BT_) * 64;  // 4096 blocks
}

DI unsigned short f2bf(float v) {
    __bf16 h = (__bf16)v;                 // RNE convert
    return __builtin_bit_cast(unsigned short, h);
}

__global__ __launch_bounds__(256)
void recon_kernel(const float* __restrict__ x, const float* __restrict__ W1,
                  const float* __restrict__ b1, const float* __restrict__ W2,
                  const float* __restrict__ b2, float* __restrict__ out)
{
    __shared__ __align__(16) unsigned short w1t[64 * 32];       // [n<64][k<32]
    __shared__ __align__(16) unsigned short w2t[32 * 64];       // [n<32][k<64]
    __shared__ __align__(16) unsigned short hb[4][2][16 * 64];  // DOUBLE-BUFFERED h^T

    // XCD-aware remap: per XCD, all 64 features of one 256-row region are
    // co-resident -> full 8-KB x rows read together, out lines merge in L2/LLC.
    const int bid   = blockIdx.x;               // 0..4095
    const int f     = (bid >> 3) & 63;
    const int btile = ((bid & 7) << 3) | (bid >> 9);

    const int tid  = threadIdx.x;
    const int lane = tid & 63;
    const int wv   = tid >> 6;
    const int l15  = lane & 15;
    const int kg   = lane >> 4;
    const int swz  = (l15 & 7) << 3;            // XOR swizzle (16-B granule)
    const bool catf = (f < 32);                 // categorical (card>1)?

    const int b0 = btile * BT_ + wv * 64;

    // ---- issue ALL x loads first: HBM latency hides under weight staging ----
    f32x4 xa[4][2];
#pragma unroll
    for (int t = 0; t < 4; ++t) {
        const float* xr = x + (size_t)(b0 + t * 16 + l15) * XROW + f * 32 + kg * 8;
        xa[t][0] = *(const f32x4*)xr;
        xa[t][1] = *(const f32x4*)(xr + 4);
    }

    // ---- stage W1^T (always) and W2^T (card>1 only) as bf16 ----
    const float* W1f = W1 + f * 2048;
    const float* W2f = W2 + f * 2048;
    {
        const int e0 = tid * 8;                 // 256 thr x 8 = 2048 elements
        f32x4 v0 = *(const f32x4*)(W1f + e0);
        f32x4 v1 = *(const f32x4*)(W1f + e0 + 4);
        if (catf) {
            f32x4 u0 = *(const f32x4*)(W2f + e0);
            f32x4 u1 = *(const f32x4*)(W2f + e0 + 4);
#pragma unroll
            for (int j = 0; j < 8; ++j) {
                int e = e0 + j;
                float u = (j < 4) ? u0[j] : u1[j - 4];
                w2t[(e & 31) * 64 + (e >> 5)] = f2bf(u);   // W2: e = k*32 + n
            }
        }
#pragma unroll
        for (int j = 0; j < 8; ++j) {
            int e = e0 + j;
            float v = (j < 4) ? v0[j] : v1[j - 4];
            w1t[(e & 63) * 32 + (e >> 6)] = f2bf(v);       // W1: e = k*64 + n
        }
    }
    __syncthreads();

    // ---- fragments (swapped-operand layout) ----
    short8 w1b[4];                               // W1[k][c]: c=l15, k=kg*8+j
#pragma unroll
    for (int nt = 0; nt < 4; ++nt)
        w1b[nt] = *(const short8*)&w1t[(nt * 16 + l15) * 32 + kg * 8];

    short8 w2b[2][2] = {};                       // W2[k][c]: c=l15, k=ks*32+kg*8+j
    if (catf) {
#pragma unroll
        for (int nt = 0; nt < 2; ++nt)
#pragma unroll
            for (int ks = 0; ks < 2; ++ks)
                w2b[nt][ks] = *(const short8*)&w2t[(nt * 16 + l15) * 64 + ks * 32 + kg * 8];
    } else {
        // card==1: only output column 0 used -> load W2[k][0] straight from
        // GLOBAL (w2t was not staged for these features!). L2-hit broadcast.
        // (validated in R4)
#pragma unroll
        for (int ks = 0; ks < 2; ++ks)
#pragma unroll
            for (int j = 0; j < 8; ++j)
                w2b[0][ks][j] = (short)f2bf(W2f[(ks * 32 + kg * 8 + j) * 32]);
    }

    f32x4 b1q[4], b2q[2];                        // fed as MFMA C-operand
#pragma unroll
    for (int nt = 0; nt < 4; ++nt) b1q[nt] = *(const f32x4*)(b1 + f * 64 + nt * 16 + kg * 4);
#pragma unroll
    for (int nt = 0; nt < 2; ++nt) b2q[nt] = *(const f32x4*)(b2 + f * 32 + nt * 16 + kg * 4);

    // output gather params (CARDS = [4,8,16,32]*8 ++ [1]*32)
    int card, off;
    if (catf) { card = 4 << (f & 3); off = (f >> 2) * 60 + card - 4; }
    else      { card = 1;            off = 480 + (f - 32); }

#pragma unroll
    for (int t = 0; t < 4; ++t) {
        unsigned short* hw = hb[wv][t & 1];      // parity buffer: no cross-tile
                                                 // LDS aliasing -> chains overlap
        short8 af;                               // x[r=l15][k=kg*8+j]
#pragma unroll
        for (int j = 0; j < 4; ++j) {
            af[j]     = (short)f2bf(xa[t][0][j]);
            af[4 + j] = (short)f2bf(xa[t][1][j]);
        }

        // GEMM1 swapped, bias in acc: lane holds h[c=nt*16+kg*4+j][r=l15]
        f32x4 c1[4];
#pragma unroll
        for (int nt = 0; nt < 4; ++nt)
            c1[nt] = __builtin_amdgcn_mfma_f32_16x16x32_bf16(w1b[nt], af, b1q[nt], 0, 0, 0);

        // ReLU -> packed bf16x4 -> wave-private swizzled LDS (no barrier)
#pragma unroll
        for (int nt = 0; nt < 4; ++nt) {
            u16x4 hv;
#pragma unroll
            for (int j = 0; j < 4; ++j) {
                float v = c1[nt][j];
                hv[j] = f2bf(v > 0.f ? v : 0.f);
            }
            *(u16x4*)&hw[(l15 * 64 + nt * 16 + kg * 4) ^ swz] = hv;
        }

        // GEMM2 A-fragments (h[r=l15][k=ks*32+kg*8+j]) from swizzled LDS
        short8 ha[2];
#pragma unroll
        for (int ks = 0; ks < 2; ++ks)
            ha[ks] = *(const short8*)&hw[(l15 * 64 + ks * 32 + kg * 8) ^ swz];

        // GEMM2 swapped, bias in acc: lane holds out[c=nt*16+kg*4+j][r=l15]
        f32x4 c2[2];
        c2[0] = __builtin_amdgcn_mfma_f32_16x16x32_bf16(w2b[0][0], ha[0], b2q[0], 0, 0, 0);
        c2[0] = __builtin_amdgcn_mfma_f32_16x16x32_bf16(w2b[0][1], ha[1], c2[0], 0, 0, 0);
        if (card == 32) {
            c2[1] = __builtin_amdgcn_mfma_f32_16x16x32_bf16(w2b[1][0], ha[0], b2q[1], 0, 0, 0);
            c2[1] = __builtin_amdgcn_mfma_f32_16x16x32_bf16(w2b[1][1], ha[1], c2[1], 0, 0, 0);
        }

        // store: each active lane writes one aligned dwordx4 (bias already in)
        const int row = b0 + t * 16 + l15;
        if (card > 1) {
            const int ntiles = (card == 32) ? 2 : 1;
            for (int nt = 0; nt < ntiles; ++nt) {
                if (kg * 4 < card - nt * 16) {
                    f32x4 v;
#pragma unroll
                    for (int j = 0; j < 4; ++j) v[j] = c2[nt][j];
                    *(f32x4*)(out + (size_t)row * TOT_ + off + nt * 16 + kg * 4) = v;
                }
            }
        } else {
            if (kg == 0)
                out[(size_t)row * TOT_ + off] = c2[0][0];
        }
    }
}

extern "C" void kernel_launch(void* const* d_in, const int* in_sizes, int n_in,
                              void* d_out, int out_size, void* d_ws, size_t ws_size,
                              hipStream_t stream) {
    const float* x  = (const float*)d_in[0];
    const float* W1 = (const float*)d_in[1];
    const float* b1 = (const float*)d_in[2];
    const float* W2 = (const float*)d_in[3];
    const float* b2 = (const float*)d_in[4];
    float* out = (float*)d_out;
    recon_kernel<<<NB_, 256, 0, stream>>>(x, W1, b1, W2, b2, out);
}